// Round 6
// baseline (522.241 us; speedup 1.0000x reference)
//
#include <hip/hip_runtime.h>
#include <hip/hip_bf16.h>

// Biattention: x:[8,2048,1024] f32, mask:[8,2048] i32
// out = concat([x, c, x+c, x-c, x*c], -1) where c = softmax(mask(x x^T)) x
//
// R6: both GEMMs moved to 256x256 tiles / 512 threads / 8 waves (2M x 4N),
// keeping the R4/R5-verified pipeline skeleton EXACTLY (same per-thread stage
// counts -> same vmcnt values, same barrier placement, same T2 swizzle).
// Intensity: 32 MFMA per wave-iter per 32KB staged (2x the 1282 tile),
// staged traffic halved. k_context: swapped mfma operands -> float4 epilogue.

typedef __attribute__((ext_vector_type(8))) __bf16 bf16x8;
typedef __attribute__((ext_vector_type(4))) float f32x4;

#define SEQ 2048
#define DIM 1024
#define NBATCH 8
#define BK 32

__device__ __forceinline__ unsigned short f2bf(float f) {
  union { __hip_bfloat16 h; unsigned short u; } cv;
  cv.h = __float2bfloat16(f);
  return cv.u;
}
__device__ __forceinline__ float bf2f(unsigned short u) {
  union { __hip_bfloat16 h; unsigned short u; } cv;
  cv.u = u;
  return __bfloat162float(cv.h);
}

__device__ __forceinline__ void load16(const void* g, void* l) {
  __builtin_amdgcn_global_load_lds(
      (const __attribute__((address_space(1))) unsigned int*)g,
      (__attribute__((address_space(3))) unsigned int*)l, 16, 0, 0);
}

// ---------------- K1: convert + transpose ----------------
__global__ __launch_bounds__(256) void k_prep(
    const float* __restrict__ x, unsigned short* __restrict__ xh,
    unsigned short* __restrict__ xl, unsigned short* __restrict__ xT) {
  __shared__ unsigned short tile[32][33];
  int b = blockIdx.z;
  int s0 = blockIdx.x * 32;
  int d0 = blockIdx.y * 32;
  int t = threadIdx.x;
  int r = t >> 3;
  int c4 = (t & 7) * 4;

  long src = (long)(b * SEQ + s0 + r) * DIM + d0 + c4;
  float4 v = *(const float4*)(x + src);
  float vv[4] = {v.x, v.y, v.z, v.w};
  unsigned short hu[4], lu[4];
#pragma unroll
  for (int j = 0; j < 4; ++j) {
    hu[j] = f2bf(vv[j]);
    float hf = bf2f(hu[j]);
    lu[j] = f2bf(vv[j] - hf);
    tile[r][c4 + j] = hu[j];
  }
  *(ushort4*)(xh + src) = make_ushort4(hu[0], hu[1], hu[2], hu[3]);
  *(ushort4*)(xl + src) = make_ushort4(lu[0], lu[1], lu[2], lu[3]);
  __syncthreads();
  unsigned short tv[4];
#pragma unroll
  for (int j = 0; j < 4; ++j) tv[j] = tile[c4 + j][r];
  long dst = (long)(b * DIM + d0 + r) * SEQ + s0 + c4;
  *(ushort4*)(xT + dst) = make_ushort4(tv[0], tv[1], tv[2], tv[3]);
}

// ---------------- K2: scores GEMM 256^2 (NT, split-bf16, symmetric, d2) ----------------
// grid 288 = 8 batch * 36 tri-blocks (8x8), 512 threads, LDS 64KB (2-resident)
#define NT_SC 96
__global__ __launch_bounds__(512, 2) void k_scores(
    const unsigned short* __restrict__ xh, const unsigned short* __restrict__ xl,
    float* __restrict__ S) {
  __shared__ unsigned short As[2][256 * BK];
  __shared__ unsigned short Bs[2][256 * BK];
  int p = blockIdx.x;            // 0..287
  int b = p & 7;                 // one batch per XCD (T1)
  int t = p >> 3;                // tri-index 0..35
  int bm = 0, rem = 8;
  while (t >= rem) { t -= rem; ++bm; --rem; }
  int bn = bm + t;
  int m0 = bm * 256;
  int n0 = bn * 256;
  const unsigned short* xh_b = xh + (long)b * SEQ * DIM;
  const unsigned short* xl_b = xl + (long)b * SEQ * DIM;
  float* S_b = S + (long)b * SEQ * SEQ;

  int tid = threadIdx.x;
  int w = tid >> 6, lane = tid & 63;
  int wr = w >> 2, wc = w & 3;       // 2M x 4N wave grid
  int l15 = lane & 15, lhi = lane >> 4;

  // staging: 1024 chunks (16B) per operand per tile, 2 per thread
  int cb0 = w * 64, cb1 = 512 + w * 64;   // wave-uniform chunk bases
  int c0 = cb0 + lane, c1 = cb1 + lane;
  int ra = c0 >> 2, rb = c1 >> 2;         // rows 0..127 / 128..255
  long aoff0 = (long)(m0 + ra) * DIM + ((c0 & 3) ^ ((ra >> 1) & 3)) * 8;
  long aoff1 = (long)(m0 + rb) * DIM + ((c1 & 3) ^ ((rb >> 1) & 3)) * 8;
  long boff0 = (long)(n0 + ra) * DIM + ((c0 & 3) ^ ((ra >> 1) & 3)) * 8;
  long boff1 = (long)(n0 + rb) * DIM + ((c1 & 3) ^ ((rb >> 1) & 3)) * 8;

#define STAGE_SC(KT, BUF)                                                   \
  {                                                                         \
    int k0_ = (KT) * BK;                                                    \
    int pp_ = k0_ >> 10;                                                    \
    int kk_ = k0_ & 1023;                                                   \
    const unsigned short* Asrc_ = (pp_ == 2) ? xl_b : xh_b;                 \
    const unsigned short* Bsrc_ = (pp_ == 1) ? xl_b : xh_b;                 \
    load16(Asrc_ + aoff0 + kk_, &As[BUF][cb0 * 8]);                         \
    load16(Asrc_ + aoff1 + kk_, &As[BUF][cb1 * 8]);                         \
    load16(Bsrc_ + boff0 + kk_, &Bs[BUF][cb0 * 8]);                         \
    load16(Bsrc_ + boff1 + kk_, &Bs[BUF][cb1 * 8]);                         \
  }

#define COMP_SC(BUF)                                                        \
  {                                                                         \
    bf16x8 af[8], bg[4];                                                    \
    _Pragma("unroll") for (int m = 0; m < 8; ++m) {                         \
      int R = wr * 128 + m * 16 + l15;                                      \
      af[m] = *(const bf16x8*)&As[BUF][R * BK + ((lhi ^ ((R >> 1) & 3)) * 8)]; \
    }                                                                       \
    _Pragma("unroll") for (int n = 0; n < 4; ++n) {                         \
      int R = wc * 64 + n * 16 + l15;                                       \
      bg[n] = *(const bf16x8*)&Bs[BUF][R * BK + ((lhi ^ ((R >> 1) & 3)) * 8)]; \
    }                                                                       \
    _Pragma("unroll") for (int m = 0; m < 8; ++m)                           \
      _Pragma("unroll") for (int n = 0; n < 4; ++n)                         \
        acc[m][n] = __builtin_amdgcn_mfma_f32_16x16x32_bf16(af[m], bg[n], acc[m][n], 0, 0, 0); \
  }

  f32x4 acc[8][4];
#pragma unroll
  for (int m = 0; m < 8; ++m)
#pragma unroll
    for (int n = 0; n < 4; ++n)
#pragma unroll
      for (int j = 0; j < 4; ++j) acc[m][n][j] = 0.0f;

  // depth-2 pipeline (R4-verified skeleton: 4 loads/stage -> vmcnt(4))
  STAGE_SC(0, 0);
  STAGE_SC(1, 1);
  for (int kt = 0; kt < NT_SC - 1; ++kt) {
    asm volatile("s_waitcnt vmcnt(4)" ::: "memory");
    __builtin_amdgcn_s_barrier();
    __builtin_amdgcn_sched_barrier(0);
    COMP_SC(kt & 1);
    __builtin_amdgcn_sched_barrier(0);
    __builtin_amdgcn_s_barrier();
    if (kt + 2 < NT_SC) STAGE_SC(kt + 2, kt & 1);
  }
  asm volatile("s_waitcnt vmcnt(0)" ::: "memory");
  __builtin_amdgcn_s_barrier();
  COMP_SC((NT_SC - 1) & 1);

#pragma unroll
  for (int m = 0; m < 8; ++m)
#pragma unroll
    for (int n = 0; n < 4; ++n)
#pragma unroll
      for (int j = 0; j < 4; ++j) {
        int r = m0 + wr * 128 + m * 16 + lhi * 4 + j;
        int c = n0 + wc * 64 + n * 16 + l15;
        S_b[(long)r * SEQ + c] = acc[m][n][j];
      }
  if (bm != bn) {
#pragma unroll
    for (int m = 0; m < 8; ++m)
#pragma unroll
      for (int n = 0; n < 4; ++n) {
        int r0 = m0 + wr * 128 + m * 16 + lhi * 4;
        int c = n0 + wc * 64 + n * 16 + l15;
        *(f32x4*)&S_b[(long)c * SEQ + r0] = acc[m][n];
      }
  }
}

// ---------------- K3: masked softmax, wave per row ----------------
__global__ __launch_bounds__(256) void k_softmax(
    const float* __restrict__ S, const int* __restrict__ mask,
    unsigned short* __restrict__ P) {
  int w = threadIdx.x >> 6, lane = threadIdx.x & 63;
  long row = (long)blockIdx.x * 4 + w;
  int b = (int)(row >> 11);
  const float* Sp = S + row * SEQ;
  const int* mp = mask + b * SEQ;
  unsigned short* Pp = P + row * SEQ;

  float sv[32];
  float mx = -__builtin_inff();
#pragma unroll
  for (int ci = 0; ci < 8; ++ci) {
    int col = ci * 256 + lane * 4;
    float4 v = *(const float4*)(Sp + col);
    int4 mk = *(const int4*)(mp + col);
    sv[ci * 4 + 0] = mk.x ? v.x : -__builtin_inff();
    sv[ci * 4 + 1] = mk.y ? v.y : -__builtin_inff();
    sv[ci * 4 + 2] = mk.z ? v.z : -__builtin_inff();
    sv[ci * 4 + 3] = mk.w ? v.w : -__builtin_inff();
    mx = fmaxf(mx, fmaxf(fmaxf(sv[ci * 4 + 0], sv[ci * 4 + 1]),
                         fmaxf(sv[ci * 4 + 2], sv[ci * 4 + 3])));
  }
#pragma unroll
  for (int off = 32; off; off >>= 1) mx = fmaxf(mx, __shfl_xor(mx, off));
  float pv[32];
  float sum = 0.0f;
#pragma unroll
  for (int i = 0; i < 32; ++i) {
    pv[i] = expf(sv[i] - mx);
    sum += pv[i];
  }
#pragma unroll
  for (int off = 32; off; off >>= 1) sum += __shfl_xor(sum, off);
  float inv = 1.0f / sum;
#pragma unroll
  for (int ci = 0; ci < 8; ++ci) {
    int col = ci * 256 + lane * 4;
    *(ushort4*)(Pp + col) = make_ushort4(
        f2bf(pv[ci * 4 + 0] * inv), f2bf(pv[ci * 4 + 1] * inv),
        f2bf(pv[ci * 4 + 2] * inv), f2bf(pv[ci * 4 + 3] * inv));
  }
}

// ---------------- K4: context GEMM 256^2 (NT, swapped-op) + epilogue, d3 ----------------
// grid 256 = 8 batch * (8 m x 4 n), 512 threads, LDS 96KB.
// mfma(bg, af): D col = q, row = d -> thread holds 4 consecutive d => float4 epilogue.
#define NT_CTX 64
__global__ __launch_bounds__(512, 2) void k_context(
    const unsigned short* __restrict__ P, const unsigned short* __restrict__ xT,
    const float* __restrict__ x, float* __restrict__ out) {
  __shared__ unsigned short As[3][256 * BK];
  __shared__ unsigned short Bs[3][256 * BK];
  int p = blockIdx.x;            // 0..255
  int b = p & 7;                 // one batch per XCD (T1)
  int q = p >> 3;                // 0..31
  int n0 = (q & 3) * 256;        // d cols; n-siblings spaced 8 -> same XCD
  int m0 = (q >> 2) * 256;       // q rows
  const unsigned short* A_b = P + (long)b * SEQ * SEQ;
  const unsigned short* B_b = xT + (long)b * DIM * SEQ;

  int tid = threadIdx.x;
  int w = tid >> 6, lane = tid & 63;
  int wr = w >> 2, wc = w & 3;
  int l15 = lane & 15, lhi = lane >> 4;

  int cb0 = w * 64, cb1 = 512 + w * 64;
  int c0 = cb0 + lane, c1 = cb1 + lane;
  int ra = c0 >> 2, rb = c1 >> 2;
  const unsigned short* Arow0 = A_b + (long)(m0 + ra) * SEQ + ((c0 & 3) ^ ((ra >> 1) & 3)) * 8;
  const unsigned short* Arow1 = A_b + (long)(m0 + rb) * SEQ + ((c1 & 3) ^ ((rb >> 1) & 3)) * 8;
  const unsigned short* Brow0 = B_b + (long)(n0 + ra) * SEQ + ((c0 & 3) ^ ((ra >> 1) & 3)) * 8;
  const unsigned short* Brow1 = B_b + (long)(n0 + rb) * SEQ + ((c1 & 3) ^ ((rb >> 1) & 3)) * 8;

#define STAGE_CTX(KT, BUF)                                \
  {                                                       \
    int kk_ = (KT) * BK;                                  \
    load16(Arow0 + kk_, &As[BUF][cb0 * 8]);               \
    load16(Arow1 + kk_, &As[BUF][cb1 * 8]);               \
    load16(Brow0 + kk_, &Bs[BUF][cb0 * 8]);               \
    load16(Brow1 + kk_, &Bs[BUF][cb1 * 8]);               \
  }

#define COMP_CTX(BUF)                                                       \
  {                                                                         \
    bf16x8 af[8], bg[4];                                                    \
    _Pragma("unroll") for (int m = 0; m < 8; ++m) {                         \
      int R = wr * 128 + m * 16 + l15;                                      \
      af[m] = *(const bf16x8*)&As[BUF][R * BK + ((lhi ^ ((R >> 1) & 3)) * 8)]; \
    }                                                                       \
    _Pragma("unroll") for (int n = 0; n < 4; ++n) {                         \
      int R = wc * 64 + n * 16 + l15;                                       \
      bg[n] = *(const bf16x8*)&Bs[BUF][R * BK + ((lhi ^ ((R >> 1) & 3)) * 8)]; \
    }                                                                       \
    _Pragma("unroll") for (int m = 0; m < 8; ++m)                           \
      _Pragma("unroll") for (int n = 0; n < 4; ++n)                         \
        acc[m][n] = __builtin_amdgcn_mfma_f32_16x16x32_bf16(bg[n], af[m], acc[m][n], 0, 0, 0); \
  }

  f32x4 acc[8][4];
#pragma unroll
  for (int m = 0; m < 8; ++m)
#pragma unroll
    for (int n = 0; n < 4; ++n)
#pragma unroll
      for (int j = 0; j < 4; ++j) acc[m][n][j] = 0.0f;

  // depth-3 pipeline (R5-verified skeleton: 4 loads/stage -> vmcnt(8)/(4)/(0))
  STAGE_CTX(0, 0);
  STAGE_CTX(1, 1);
  STAGE_CTX(2, 2);
  int cur = 0;
  for (int kt = 0; kt < NT_CTX - 2; ++kt) {
    asm volatile("s_waitcnt vmcnt(8)" ::: "memory");
    __builtin_amdgcn_s_barrier();
    __builtin_amdgcn_sched_barrier(0);
    COMP_CTX(cur);
    __builtin_amdgcn_sched_barrier(0);
    __builtin_amdgcn_s_barrier();
    if (kt + 3 < NT_CTX) STAGE_CTX(kt + 3, cur);
    cur = (cur == 2) ? 0 : cur + 1;
  }
  asm volatile("s_waitcnt vmcnt(4)" ::: "memory");
  __builtin_amdgcn_s_barrier();
  COMP_CTX((NT_CTX - 2) % 3);
  asm volatile("s_waitcnt vmcnt(0)" ::: "memory");
  __builtin_amdgcn_s_barrier();
  COMP_CTX((NT_CTX - 1) % 3);

  const float* x_b = x + (long)b * SEQ * DIM;
  float* out_b = out + (long)b * SEQ * (5 * DIM);
#pragma unroll
  for (int m = 0; m < 8; ++m)
#pragma unroll
    for (int n = 0; n < 4; ++n) {
      int qi = m0 + wr * 128 + m * 16 + l15;          // col index = q
      int d = n0 + wc * 64 + n * 16 + lhi * 4;        // row index = d (4 consec)
      f32x4 c4 = acc[m][n];
      f32x4 xv = *(const f32x4*)&x_b[(long)qi * DIM + d];
      long base = (long)qi * (5 * DIM) + d;
      *(f32x4*)&out_b[base] = xv;
      *(f32x4*)&out_b[base + DIM] = c4;
      *(f32x4*)&out_b[base + 2 * DIM] = xv + c4;
      *(f32x4*)&out_b[base + 3 * DIM] = xv - c4;
      *(f32x4*)&out_b[base + 4 * DIM] = xv * c4;
    }
}

extern "C" void kernel_launch(void* const* d_in, const int* in_sizes, int n_in,
                              void* d_out, int out_size, void* d_ws, size_t ws_size,
                              hipStream_t stream) {
  const float* x = (const float*)d_in[0];
  const int* mask = (const int*)d_in[1];
  float* out = (float*)d_out;
  char* ws = (char*)d_ws;

  const size_t HB = (size_t)NBATCH * SEQ * DIM * 2;
  unsigned short* xh = (unsigned short*)ws;
  unsigned short* xl = (unsigned short*)(ws + HB);
  unsigned short* xT = (unsigned short*)(ws + 2 * HB);
  unsigned short* P = (unsigned short*)(ws + 3 * HB);
  const size_t PB = (size_t)NBATCH * SEQ * SEQ * 2;
  const size_t SB = (size_t)NBATCH * SEQ * SEQ * 4;
  float* S;
  if (ws_size >= 3 * HB + PB + SB) {
    S = (float*)(ws + 3 * HB + PB);
  } else {
    S = (float*)d_out;  // S dead before K4 writes out
  }

  k_prep<<<dim3(SEQ / 32, DIM / 32, NBATCH), 256, 0, stream>>>(x, xh, xl, xT);
  k_scores<<<dim3(288, 1, 1), 512, 0, stream>>>(xh, xl, S);
  k_softmax<<<NBATCH * SEQ / 4, 256, 0, stream>>>(S, mask, P);
  k_context<<<dim3(256, 1, 1), 512, 0, stream>>>(P, xT, x, out);
}

// Round 7
// 409.506 us; speedup vs baseline: 1.2753x; 1.2753x over previous
//
#include <hip/hip_runtime.h>
#include <hip/hip_bf16.h>

// Biattention: x:[8,2048,1024] f32, mask:[8,2048] i32
// out = concat([x, c, x+c, x-c, x*c], -1) where c = softmax(mask(x x^T)) x
//
// R7: k_scores reverted to R5-exact (128^2, depth-3 counted vmcnt — 176us known).
// k_context rewritten: 256^2 tile, BK=64, 8 waves, 4-phase-per-K-tile interleave
// (T3+T4): each phase { ds_reads + 2 global_load_lds -> barrier -> lgkmcnt(0)
// + sched_barrier -> setprio(1) -> 16 MFMA -> setprio(0) -> barrier }, single
// vmcnt(4) per K-tile (6-phase staging lookahead), grid 256 = 1 balanced round.

typedef __attribute__((ext_vector_type(8))) __bf16 bf16x8;
typedef __attribute__((ext_vector_type(4))) float f32x4;

#define SEQ 2048
#define DIM 1024
#define NBATCH 8
#define BK 32

__device__ __forceinline__ unsigned short f2bf(float f) {
  union { __hip_bfloat16 h; unsigned short u; } cv;
  cv.h = __float2bfloat16(f);
  return cv.u;
}
__device__ __forceinline__ float bf2f(unsigned short u) {
  union { __hip_bfloat16 h; unsigned short u; } cv;
  cv.u = u;
  return __bfloat162float(cv.h);
}

__device__ __forceinline__ void load16(const void* g, void* l) {
  __builtin_amdgcn_global_load_lds(
      (const __attribute__((address_space(1))) unsigned int*)g,
      (__attribute__((address_space(3))) unsigned int*)l, 16, 0, 0);
}

// ---------------- K1: convert + transpose ----------------
__global__ __launch_bounds__(256) void k_prep(
    const float* __restrict__ x, unsigned short* __restrict__ xh,
    unsigned short* __restrict__ xl, unsigned short* __restrict__ xT) {
  __shared__ unsigned short tile[32][33];
  int b = blockIdx.z;
  int s0 = blockIdx.x * 32;
  int d0 = blockIdx.y * 32;
  int t = threadIdx.x;
  int r = t >> 3;
  int c4 = (t & 7) * 4;

  long src = (long)(b * SEQ + s0 + r) * DIM + d0 + c4;
  float4 v = *(const float4*)(x + src);
  float vv[4] = {v.x, v.y, v.z, v.w};
  unsigned short hu[4], lu[4];
#pragma unroll
  for (int j = 0; j < 4; ++j) {
    hu[j] = f2bf(vv[j]);
    float hf = bf2f(hu[j]);
    lu[j] = f2bf(vv[j] - hf);
    tile[r][c4 + j] = hu[j];
  }
  *(ushort4*)(xh + src) = make_ushort4(hu[0], hu[1], hu[2], hu[3]);
  *(ushort4*)(xl + src) = make_ushort4(lu[0], lu[1], lu[2], lu[3]);
  __syncthreads();
  unsigned short tv[4];
#pragma unroll
  for (int j = 0; j < 4; ++j) tv[j] = tile[c4 + j][r];
  long dst = (long)(b * DIM + d0 + r) * SEQ + s0 + c4;
  *(ushort4*)(xT + dst) = make_ushort4(tv[0], tv[1], tv[2], tv[3]);
}

// shared compute macro (R5-exact, used by k_scores)
#define COMPUTE_TILE(ARR_A, ARR_B, BUF)                                     \
  {                                                                         \
    bf16x8 af[4], bg[4];                                                    \
    _Pragma("unroll") for (int m = 0; m < 4; ++m) {                         \
      int R = wr * 64 + m * 16 + l15;                                       \
      af[m] = *(const bf16x8*)&ARR_A[BUF][R * BK + ((lhi ^ ((R >> 1) & 3)) * 8)]; \
    }                                                                       \
    _Pragma("unroll") for (int n = 0; n < 4; ++n) {                         \
      int R = wc * 64 + n * 16 + l15;                                       \
      bg[n] = *(const bf16x8*)&ARR_B[BUF][R * BK + ((lhi ^ ((R >> 1) & 3)) * 8)]; \
    }                                                                       \
    _Pragma("unroll") for (int m = 0; m < 4; ++m)                           \
      _Pragma("unroll") for (int n = 0; n < 4; ++n)                         \
        acc[m][n] = __builtin_amdgcn_mfma_f32_16x16x32_bf16(af[m], bg[n], acc[m][n], 0, 0, 0); \
  }

// ---------------- K2: scores GEMM (R5-exact: 128^2, split-bf16, symmetric, d3) ----------------
#define NT_SC 96
__global__ __launch_bounds__(256) void k_scores(
    const unsigned short* __restrict__ xh, const unsigned short* __restrict__ xl,
    float* __restrict__ S) {
  __shared__ unsigned short As[3][128 * BK];
  __shared__ unsigned short Bs[3][128 * BK];
  int p = blockIdx.x + 136 * blockIdx.z;   // 0..1087
  int b = p & 7;                            // one batch per XCD
  int t = p >> 3;                           // tri-index 0..135
  int bm = 0, rem = 16;
  while (t >= rem) { t -= rem; ++bm; --rem; }
  int bn = bm + t;
  int m0 = bm * 128;
  int n0 = bn * 128;
  const unsigned short* xh_b = xh + (long)b * SEQ * DIM;
  const unsigned short* xl_b = xl + (long)b * SEQ * DIM;
  float* S_b = S + (long)b * SEQ * SEQ;

  int tid = threadIdx.x;
  int w = tid >> 6, lane = tid & 63;
  int wr = w >> 1, wc = w & 1;
  int l15 = lane & 15, lhi = lane >> 4;

  int cbase0 = w * 64, cbase1 = 256 + w * 64;
  int c0 = cbase0 + lane, c1 = cbase1 + lane;
  int row0 = c0 >> 2, row1 = c1 >> 2;
  long aoff0 = (long)(m0 + row0) * DIM + ((c0 & 3) ^ ((row0 >> 1) & 3)) * 8;
  long aoff1 = (long)(m0 + row1) * DIM + ((c1 & 3) ^ ((row1 >> 1) & 3)) * 8;
  long boff0 = (long)(n0 + row0) * DIM + ((c0 & 3) ^ ((row0 >> 1) & 3)) * 8;
  long boff1 = (long)(n0 + row1) * DIM + ((c1 & 3) ^ ((row1 >> 1) & 3)) * 8;

#define STAGE_SC(KT, BUF)                                                   \
  {                                                                         \
    int k0_ = (KT) * BK;                                                    \
    int pp_ = k0_ >> 10;                                                    \
    int kk_ = k0_ & 1023;                                                   \
    const unsigned short* As_ = (pp_ == 2) ? xl_b : xh_b;                   \
    const unsigned short* Bs_ = (pp_ == 1) ? xl_b : xh_b;                   \
    load16(As_ + aoff0 + kk_, &As[BUF][cbase0 * 8]);                        \
    load16(As_ + aoff1 + kk_, &As[BUF][cbase1 * 8]);                        \
    load16(Bs_ + boff0 + kk_, &Bs[BUF][cbase0 * 8]);                        \
    load16(Bs_ + boff1 + kk_, &Bs[BUF][cbase1 * 8]);                        \
  }

  f32x4 acc[4][4];
#pragma unroll
  for (int m = 0; m < 4; ++m)
#pragma unroll
    for (int n = 0; n < 4; ++n)
#pragma unroll
      for (int j = 0; j < 4; ++j) acc[m][n][j] = 0.0f;

  STAGE_SC(0, 0);
  STAGE_SC(1, 1);
  STAGE_SC(2, 2);
  int cur = 0;
  for (int kt = 0; kt < NT_SC - 2; ++kt) {
    asm volatile("s_waitcnt vmcnt(8)" ::: "memory");
    __builtin_amdgcn_s_barrier();
    __builtin_amdgcn_sched_barrier(0);
    COMPUTE_TILE(As, Bs, cur);
    __builtin_amdgcn_sched_barrier(0);
    __builtin_amdgcn_s_barrier();
    if (kt + 3 < NT_SC) STAGE_SC(kt + 3, cur);
    cur = (cur == 2) ? 0 : cur + 1;
  }
  asm volatile("s_waitcnt vmcnt(4)" ::: "memory");
  __builtin_amdgcn_s_barrier();
  COMPUTE_TILE(As, Bs, (NT_SC - 2) % 3);
  asm volatile("s_waitcnt vmcnt(0)" ::: "memory");
  __builtin_amdgcn_s_barrier();
  COMPUTE_TILE(As, Bs, (NT_SC - 1) % 3);

#pragma unroll
  for (int m = 0; m < 4; ++m)
#pragma unroll
    for (int n = 0; n < 4; ++n)
#pragma unroll
      for (int j = 0; j < 4; ++j) {
        int r = m0 + wr * 64 + m * 16 + lhi * 4 + j;
        int c = n0 + wc * 64 + n * 16 + l15;
        S_b[(long)r * SEQ + c] = acc[m][n][j];
      }
  if (bm != bn) {
#pragma unroll
    for (int m = 0; m < 4; ++m)
#pragma unroll
      for (int n = 0; n < 4; ++n) {
        int r0 = m0 + wr * 64 + m * 16 + lhi * 4;
        int c = n0 + wc * 64 + n * 16 + l15;
        *(f32x4*)&S_b[(long)c * SEQ + r0] = acc[m][n];
      }
  }
}

// ---------------- K3: masked softmax, wave per row ----------------
__global__ __launch_bounds__(256) void k_softmax(
    const float* __restrict__ S, const int* __restrict__ mask,
    unsigned short* __restrict__ P) {
  int w = threadIdx.x >> 6, lane = threadIdx.x & 63;
  long row = (long)blockIdx.x * 4 + w;
  int b = (int)(row >> 11);
  const float* Sp = S + row * SEQ;
  const int* mp = mask + b * SEQ;
  unsigned short* Pp = P + row * SEQ;

  float sv[32];
  float mx = -__builtin_inff();
#pragma unroll
  for (int ci = 0; ci < 8; ++ci) {
    int col = ci * 256 + lane * 4;
    float4 v = *(const float4*)(Sp + col);
    int4 mk = *(const int4*)(mp + col);
    sv[ci * 4 + 0] = mk.x ? v.x : -__builtin_inff();
    sv[ci * 4 + 1] = mk.y ? v.y : -__builtin_inff();
    sv[ci * 4 + 2] = mk.z ? v.z : -__builtin_inff();
    sv[ci * 4 + 3] = mk.w ? v.w : -__builtin_inff();
    mx = fmaxf(mx, fmaxf(fmaxf(sv[ci * 4 + 0], sv[ci * 4 + 1]),
                         fmaxf(sv[ci * 4 + 2], sv[ci * 4 + 3])));
  }
#pragma unroll
  for (int off = 32; off; off >>= 1) mx = fmaxf(mx, __shfl_xor(mx, off));
  float pv[32];
  float sum = 0.0f;
#pragma unroll
  for (int i = 0; i < 32; ++i) {
    pv[i] = expf(sv[i] - mx);
    sum += pv[i];
  }
#pragma unroll
  for (int off = 32; off; off >>= 1) sum += __shfl_xor(sum, off);
  float inv = 1.0f / sum;
#pragma unroll
  for (int ci = 0; ci < 8; ++ci) {
    int col = ci * 256 + lane * 4;
    *(ushort4*)(Pp + col) = make_ushort4(
        f2bf(pv[ci * 4 + 0] * inv), f2bf(pv[ci * 4 + 1] * inv),
        f2bf(pv[ci * 4 + 2] * inv), f2bf(pv[ci * 4 + 3] * inv));
  }
}

// ---------------- K4: context GEMM 256^2 BK=64, 4-phase interleave ----------------
// LDS layout per operand: [buf][kk][R][s4'] ushort idx = buf*16384 + kk*8192 + R*32 + s4'*8
// where s4' = s4 ^ ((R>>1)&3)  (read-side XOR is per-thread constant).
// Staging: linear LDS dest + inverse-swizzled global source (rule #21).
// Phase p of K-tile kt stages: p0: A-kk1(kt+1), p1: B-kk1(kt+1),
// p2: A-kk0(kt+2), p3: B-kk0(kt+2). One vmcnt(4) per K-tile at the p3 barrier.
#define NT_CTX 32
__global__ __launch_bounds__(512, 2) void k_context(
    const unsigned short* __restrict__ P, const unsigned short* __restrict__ xT,
    const float* __restrict__ x, float* __restrict__ out) {
  __shared__ unsigned short As[2 * 16384];  // 64 KB
  __shared__ unsigned short Bs[2 * 16384];  // 64 KB
  int p = blockIdx.x;            // 0..255
  int b = p & 7;                 // one batch per XCD (T1)
  int q = p >> 3;                // 0..31
  int n0 = (q & 3) * 256;        // d cols
  int m0 = (q >> 2) * 256;       // q rows
  const unsigned short* A_b = P + (long)b * SEQ * SEQ;
  const unsigned short* B_b = xT + (long)b * DIM * SEQ;

  int tid = threadIdx.x;
  int w = tid >> 6, lane = tid & 63;
  int wr = w >> 2, wc = w & 3;          // 2M x 4N waves; per-wave 128x64
  int l15 = lane & 15, lhi = lane >> 4;

  // ---- staging constants: per kk-half, 1024 chunks; wave w covers cids w*128..+127
  int c0 = w * 128 + lane, c1 = w * 128 + 64 + lane;
  int R0 = c0 >> 2, R1 = c1 >> 2;
  int sw0 = ((c0 & 3) ^ ((R0 >> 1) & 3)) * 8;
  int sw1 = ((c1 & 3) ^ ((R1 >> 1) & 3)) * 8;
  const unsigned short* PA0 = A_b + (long)(m0 + R0) * SEQ + sw0;
  const unsigned short* PA1 = A_b + (long)(m0 + R1) * SEQ + sw1;
  const unsigned short* PB0 = B_b + (long)(n0 + R0) * SEQ + sw0;
  const unsigned short* PB1 = B_b + (long)(n0 + R1) * SEQ + sw1;
  int ldg0 = (w * 128) * 8;        // ushort idx of group base (lane offset implicit)
  int ldg1 = (w * 128 + 64) * 8;

#define STG_A(KT, KK, BUF)                                              \
  {                                                                     \
    load16(PA0 + (KT) * 64 + (KK) * 32, &As[(BUF)*16384 + (KK)*8192 + ldg0]); \
    load16(PA1 + (KT) * 64 + (KK) * 32, &As[(BUF)*16384 + (KK)*8192 + ldg1]); \
  }
#define STG_B(KT, KK, BUF)                                              \
  {                                                                     \
    load16(PB0 + (KT) * 64 + (KK) * 32, &Bs[(BUF)*16384 + (KK)*8192 + ldg0]); \
    load16(PB1 + (KT) * 64 + (KK) * 32, &Bs[(BUF)*16384 + (KK)*8192 + ldg1]); \
  }

  // ---- fragment-read constants
  int swr = (lhi ^ ((l15 >> 1) & 3)) * 8;   // per-thread constant XOR slot
  int arow = (wr * 128 + l15) * 32;          // + m*512 (+ kk*8192 + buf*16384)
  int brow = (wc * 64 + l15) * 32;           // + n*512

#define RD_BG(BUF, KK)                                                        \
  _Pragma("unroll") for (int n = 0; n < 4; ++n)                               \
      bg[n] = *(const bf16x8*)&Bs[(BUF)*16384 + (KK)*8192 + brow + n * 512 + swr];
#define RD_AF(BUF, KK, MB)                                                    \
  _Pragma("unroll") for (int m = 0; m < 4; ++m)                               \
      af[m] = *(const bf16x8*)&As[(BUF)*16384 + (KK)*8192 + arow + ((MB)*4 + m) * 512 + swr];
#define DO_MFMA(MB)                                                           \
  _Pragma("unroll") for (int m = 0; m < 4; ++m)                               \
      _Pragma("unroll") for (int n = 0; n < 4; ++n)                           \
          acc[(MB)*4 + m][n] = __builtin_amdgcn_mfma_f32_16x16x32_bf16(       \
              bg[n], af[m], acc[(MB)*4 + m][n], 0, 0, 0);
#define PH_SYNC_MFMA(MB)                                                      \
  __builtin_amdgcn_s_barrier();                                               \
  asm volatile("s_waitcnt lgkmcnt(0)" ::: "memory");                          \
  __builtin_amdgcn_sched_barrier(0);                                          \
  __builtin_amdgcn_s_setprio(1);                                              \
  DO_MFMA(MB);                                                                \
  __builtin_amdgcn_s_setprio(0);                                              \
  __builtin_amdgcn_sched_barrier(0);

  f32x4 acc[8][4];
#pragma unroll
  for (int m = 0; m < 8; ++m)
#pragma unroll
    for (int n = 0; n < 4; ++n)
#pragma unroll
      for (int j = 0; j < 4; ++j) acc[m][n][j] = 0.0f;

  // prologue: kt0 full (8 loads) + kt1 kk0 (4 loads); drain kt0 -> vmcnt(4)
  STG_A(0, 0, 0); STG_B(0, 0, 0);
  STG_A(0, 1, 0); STG_B(0, 1, 0);
  STG_A(1, 0, 1); STG_B(1, 0, 1);
  asm volatile("s_waitcnt vmcnt(4)" ::: "memory");
  __builtin_amdgcn_s_barrier();

  for (int kt = 0; kt < NT_CTX; ++kt) {
    int c = kt & 1, o = c ^ 1;
    bf16x8 af[4], bg[4];
    // phase 0: kk0, m0-3 (+bg kk0)
    RD_AF(c, 0, 0); RD_BG(c, 0);
    if (kt + 1 < NT_CTX) STG_A(kt + 1, 1, o);
    PH_SYNC_MFMA(0);
    __builtin_amdgcn_s_barrier();
    // phase 1: kk0, m4-7 (bg kept in regs)
    RD_AF(c, 0, 1);
    if (kt + 1 < NT_CTX) STG_B(kt + 1, 1, o);
    PH_SYNC_MFMA(1);
    __builtin_amdgcn_s_barrier();
    // phase 2: kk1, m0-3 (+bg kk1)
    RD_AF(c, 1, 0); RD_BG(c, 1);
    if (kt + 2 < NT_CTX) STG_A(kt + 2, 0, c);
    PH_SYNC_MFMA(0);
    __builtin_amdgcn_s_barrier();
    // phase 3: kk1, m4-7
    RD_AF(c, 1, 1);
    if (kt + 2 < NT_CTX) STG_B(kt + 2, 0, c);
    PH_SYNC_MFMA(1);
    // K-tile boundary: counted wait, then phase-3 closing barrier = boundary barrier
    if (kt < NT_CTX - 2) {
      asm volatile("s_waitcnt vmcnt(4)" ::: "memory");
    } else if (kt == NT_CTX - 2) {
      asm volatile("s_waitcnt vmcnt(0)" ::: "memory");
    }
    __builtin_amdgcn_s_barrier();
  }

  // epilogue: swapped-operand C layout -> thread holds 4 consecutive d (f32x4)
  const float* x_b = x + (long)b * SEQ * DIM;
  float* out_b = out + (long)b * SEQ * (5 * DIM);
#pragma unroll
  for (int m = 0; m < 8; ++m)
#pragma unroll
    for (int n = 0; n < 4; ++n) {
      int qi = m0 + wr * 128 + m * 16 + l15;      // col index = q
      int d = n0 + wc * 64 + n * 16 + lhi * 4;    // row index = d (4 consec)
      f32x4 c4 = acc[m][n];
      f32x4 xv = *(const f32x4*)&x_b[(long)qi * DIM + d];
      long base = (long)qi * (5 * DIM) + d;
      *(f32x4*)&out_b[base] = xv;
      *(f32x4*)&out_b[base + DIM] = c4;
      *(f32x4*)&out_b[base + 2 * DIM] = xv + c4;
      *(f32x4*)&out_b[base + 3 * DIM] = xv - c4;
      *(f32x4*)&out_b[base + 4 * DIM] = xv * c4;
    }
}

extern "C" void kernel_launch(void* const* d_in, const int* in_sizes, int n_in,
                              void* d_out, int out_size, void* d_ws, size_t ws_size,
                              hipStream_t stream) {
  const float* x = (const float*)d_in[0];
  const int* mask = (const int*)d_in[1];
  float* out = (float*)d_out;
  char* ws = (char*)d_ws;

  const size_t HB = (size_t)NBATCH * SEQ * DIM * 2;
  unsigned short* xh = (unsigned short*)ws;
  unsigned short* xl = (unsigned short*)(ws + HB);
  unsigned short* xT = (unsigned short*)(ws + 2 * HB);
  unsigned short* P = (unsigned short*)(ws + 3 * HB);
  const size_t PB = (size_t)NBATCH * SEQ * SEQ * 2;
  const size_t SB = (size_t)NBATCH * SEQ * SEQ * 4;
  float* S;
  if (ws_size >= 3 * HB + PB + SB) {
    S = (float*)(ws + 3 * HB + PB);
  } else {
    S = (float*)d_out;  // S dead before K4 writes out
  }

  k_prep<<<dim3(SEQ / 32, DIM / 32, NBATCH), 256, 0, stream>>>(x, xh, xl, xT);
  k_scores<<<dim3(136, 1, NBATCH), 256, 0, stream>>>(xh, xl, S);
  k_softmax<<<NBATCH * SEQ / 4, 256, 0, stream>>>(S, mask, P);
  k_context<<<dim3(256, 1, 1), 512, 0, stream>>>(P, xT, x, out);
}